// Round 8
// baseline (388.014 us; speedup 1.0000x reference)
//
#include <hip/hip_runtime.h>
#include <math.h>

// Problem constants
#define DM 1024      // d_model
#define LL 2048      // sequence length
#define BB 4         // batch
#define HH 16        // heads
#define HD 64        // head dim
#define CC 64        // chunk size
#define NC (LL / CC) // 32 chunks
#define EPSC 1e-6f
#define PS 72        // padded LDS stride (elements) for VALU-written 64-wide tiles

typedef __attribute__((ext_vector_type(8))) short short8;      // 8 bf16
typedef __attribute__((ext_vector_type(8))) _Float16 half8;    // 8 f16
typedef __attribute__((ext_vector_type(4))) float floatx4;     // MFMA acc

__device__ __forceinline__ float featf(float x) { return x > 0.f ? x + 1.f : __expf(x); }

// round-to-nearest-even f32 -> bf16 bits
__device__ __forceinline__ unsigned short f2bf(float f) {
    unsigned int u = __builtin_bit_cast(unsigned int, f);
    u = (u + 0x7FFFu + ((u >> 16) & 1u)) >> 16;
    return (unsigned short)u;
}

// 8x f32 -> 8x bf16 via hardware pk converts (RNE, matches f2bf)
__device__ __forceinline__ uint4 cvt8(float4 a, float4 b) {
    uint4 r;
    asm("v_cvt_pk_bf16_f32 %0, %1, %2" : "=v"(r.x) : "v"(a.x), "v"(a.y));
    asm("v_cvt_pk_bf16_f32 %0, %1, %2" : "=v"(r.y) : "v"(a.z), "v"(a.w));
    asm("v_cvt_pk_bf16_f32 %0, %1, %2" : "=v"(r.z) : "v"(b.x), "v"(b.y));
    asm("v_cvt_pk_bf16_f32 %0, %1, %2" : "=v"(r.w) : "v"(b.z), "v"(b.w));
    return r;
}

__device__ __forceinline__ void gload_lds16(const void* g, void* l) {
    __builtin_amdgcn_global_load_lds(
        (const __attribute__((address_space(1))) void*)g,
        (__attribute__((address_space(3))) void*)l,
        16, 0, 0);
}

// Stage a 64x64 2-byte-element tile (8 KB) global -> LDS, XOR-8 chunk swizzle
// baked into the SOURCE address. LDS: row*128B + slot*16B, slot = g ^ (row&7).
__device__ __forceinline__ void stage_tile(const void* gp_, int rowstride,
                                           char* lds_base, int tid) {
    const unsigned short* gp = (const unsigned short*)gp_;
#pragma unroll
    for (int m = 0; m < 2; ++m) {
        const int row = m * 32 + (tid >> 3);
        const int g = (tid & 7) ^ (row & 7);
        gload_lds16(gp + (size_t)row * rowstride + g * 8,
                    lds_base + m * 4096 + tid * 16);
    }
}
__device__ __forceinline__ half8 frag_ldh(const char* base, int row, int kc) {
    return *(const half8*)(base + row * 128 + (((kc) ^ (row & 7)) << 4));
}

// ===========================================================================
// prep: fused input-convert (f32->bf16, deep-MLP batched) + weight
// transpose/convert. Blocks [0,1536): convert q/k/v (512 blocks each; 8
// uint4-units per thread, all 16 float4 loads in flight before stores).
// Blocks [1536,2560): the 4 weight transposes.
// ===========================================================================
__global__ __launch_bounds__(256) void prep(
    const float* __restrict__ q, const float* __restrict__ k,
    const float* __restrict__ v,
    const float* __restrict__ W0, const float* __restrict__ W1,
    const float* __restrict__ W2, const float* __restrict__ W3,
    unsigned short* __restrict__ qb, unsigned short* __restrict__ kb,
    unsigned short* __restrict__ vb,
    unsigned short* __restrict__ T0, unsigned short* __restrict__ T1,
    unsigned short* __restrict__ T2, unsigned short* __restrict__ T3)
{
    __shared__ float tile[64][65];
    const int bid = blockIdx.x;
    const int tid = threadIdx.x;
    if (bid < 1536) {
        const int sel = bid >> 9;       // 512 blocks per tensor
        const int ib = bid & 511;
        const float* src = (sel == 0) ? q : (sel == 1) ? k : v;
        unsigned short* dst = (sel == 0) ? qb : (sel == 1) ? kb : vb;
        const size_t u0 = (size_t)ib * 2048 + tid;   // uint4-unit index
        float4 x[8], y[8];
#pragma unroll
        for (int e = 0; e < 8; ++e) {
            const size_t u = u0 + (size_t)e * 256;
            x[e] = ((const float4*)src)[u * 2];
            y[e] = ((const float4*)src)[u * 2 + 1];
        }
#pragma unroll
        for (int e = 0; e < 8; ++e)
            ((uint4*)dst)[u0 + (size_t)e * 256] = cvt8(x[e], y[e]);
    } else {
        const int tb = bid - 1536;
        const int sel = tb >> 8;        // 256 blocks per weight
        const int rem = tb & 255;
        const float* W = (sel == 0) ? W0 : (sel == 1) ? W1 : (sel == 2) ? W2 : W3;
        unsigned short* Wt = (sel == 0) ? T0 : (sel == 1) ? T1 : (sel == 2) ? T2 : T3;
        const int r0 = (rem >> 4) * 64, c0 = (rem & 15) * 64;
#pragma unroll
        for (int e = 0; e < 16; ++e) {
            const int idx = e * 256 + tid;
            const int r = idx >> 6, c = idx & 63;
            tile[r][c] = W[(size_t)(r0 + r) * DM + c0 + c];
        }
        __syncthreads();
#pragma unroll
        for (int e = 0; e < 16; ++e) {
            const int idx = e * 256 + tid;
            const int co = idx >> 6, ro = idx & 63;
            Wt[(size_t)(c0 + co) * DM + r0 + ro] = f2bf(tile[ro][co]);
        }
    }
}

// ===========================================================================
// gemm_qkv3: three projection GEMMs, one 1D dispatch.
//  - bijective XCD-chunk swizzle (round-5: FETCH 200->49 MB)
//  - conflict-free super-row LDS layout (round-7: 6.29M->0 conflicts)
//  - round-8: 2-phase double buffer. Old loop issued 4 gload_lds then
//    immediately drained them at __syncthreads (zero cover) with only ~2
//    blocks/CU resident. Now: stage tile t+1 into buf^1 BEFORE ds_read+MFMA
//    of tile t (loads fly under ~300-400cy of compute), one
//    vmcnt(0)+barrier per tile. k0+32 stage always in-bounds; k0+64 stage
//    wraps (&1023) to a dead re-stage of tile 0 on the last iteration.
// sel 0: Q (act, f16)  sel 1: K (act, KT-chunk)  sel 2: V.
// ===========================================================================
#define QKV_STAGE(BUF, KS)                                                    \
    do {                                                                      \
        gload_lds16(Xa + (KS), &As[BUF][(size_t)tid * 8]);                    \
        gload_lds16(Xb + (KS), &As[BUF][(size_t)(256 + tid) * 8]);            \
        gload_lds16(Wa + (KS), &Bs[BUF][(size_t)tid * 8]);                    \
        gload_lds16(Wb + (KS), &Bs[BUF][(size_t)(256 + tid) * 8]);            \
    } while (0)

#define QKV_COMPUTE(BUF)                                                      \
    do {                                                                      \
        short8 af[4], bf[4];                                                  \
        _Pragma("unroll")                                                     \
        for (int mt = 0; mt < 4; ++mt) {                                      \
            const int rr = wr * 64 + mt * 16 + fm;                            \
            af[mt] = *(const short8*)(&As[BUF][rr * 32 +                      \
                     ((fq ^ ((rr >> 1) & 3)) << 3)]);                         \
        }                                                                     \
        _Pragma("unroll")                                                     \
        for (int nt = 0; nt < 4; ++nt) {                                      \
            const int rr = wc * 64 + nt * 16 + fm;                            \
            bf[nt] = *(const short8*)(&Bs[BUF][rr * 32 +                      \
                     ((fq ^ ((rr >> 1) & 3)) << 3)]);                         \
        }                                                                     \
        _Pragma("unroll")                                                     \
        for (int mt = 0; mt < 4; ++mt)                                        \
            _Pragma("unroll")                                                 \
            for (int nt = 0; nt < 4; ++nt)                                    \
                acc[mt][nt] = __builtin_amdgcn_mfma_f32_16x16x32_bf16(        \
                    af[mt], bf[nt], acc[mt][nt], 0, 0, 0);                    \
    } while (0)

#define GEMM_SYNC()                                                           \
    do {                                                                      \
        __builtin_amdgcn_sched_barrier(0);                                    \
        asm volatile("s_waitcnt vmcnt(0) lgkmcnt(0)" ::: "memory");           \
        __builtin_amdgcn_s_barrier();                                         \
        __builtin_amdgcn_sched_barrier(0);                                    \
    } while (0)

__global__ __launch_bounds__(256) void gemm_qkv3(
    const unsigned short* __restrict__ qb, const unsigned short* __restrict__ kb,
    const unsigned short* __restrict__ vb,
    const unsigned short* __restrict__ Wqt, const unsigned short* __restrict__ Wkt,
    const unsigned short* __restrict__ Wvt,
    const float* __restrict__ bq, const float* __restrict__ bk,
    const float* __restrict__ bv,
    _Float16* __restrict__ Qh, _Float16* __restrict__ KTp,
    _Float16* __restrict__ Vh)
{
    __shared__ __align__(16) unsigned short As[2][128 * 32];
    __shared__ __align__(16) unsigned short Bs[2][128 * 32];

    // bijective XCD swizzle: XCD x gets swz in [x*192, (x+1)*192)
    const int bid = blockIdx.x;
    const int swz = (bid & 7) * 192 + (bid >> 3);
    const int sel = swz >> 9;          // 512 tiles per sel
    const int tt = swz & 511;
    const int n0 = (tt & 7) * 128, m0 = (tt >> 3) * 128;

    const unsigned short* X = (sel == 0) ? qb : (sel == 1) ? kb : vb;
    const unsigned short* Wt = (sel == 0) ? Wqt : (sel == 1) ? Wkt : Wvt;
    const float* bias = (sel == 0) ? bq : (sel == 1) ? bk : bv;

    const int tid = threadIdx.x;
    const int lane = tid & 63;
    const int w = tid >> 6;
    const int wr = w >> 1, wc = w & 1;
    const int fm = lane & 15;
    const int fq = lane >> 4;

    floatx4 acc[4][4];
#pragma unroll
    for (int i = 0; i < 4; ++i)
#pragma unroll
        for (int j = 0; j < 4; ++j) acc[i][j] = (floatx4){0.f, 0.f, 0.f, 0.f};

    // staging map: seg t -> super-row s=t>>3, half b=(t>>2)&1, slot sl=t&3;
    // global row rr = 2s+b, col-group g = sl ^ (s&3). t+256: rr+64, same g.
    const int sseg = tid >> 3;
    const int r0 = 2 * sseg + ((tid >> 2) & 1);
    const int g0 = (tid & 3) ^ (sseg & 3);
    const unsigned short* Xa = X + (size_t)(m0 + r0) * DM + g0 * 8;
    const unsigned short* Xb = Xa + (size_t)64 * DM;
    const unsigned short* Wa = Wt + (size_t)(n0 + r0) * DM + g0 * 8;
    const unsigned short* Wb = Wa + (size_t)64 * DM;

    // prologue: tile 0 -> buf 0
    QKV_STAGE(0, 0);
    GEMM_SYNC();

    for (int k0 = 0; k0 < DM; k0 += 64) {
        // phase A: stage t+1 (k0+32, always < DM) under compute of t (buf0)
        QKV_STAGE(1, k0 + 32);
        QKV_COMPUTE(0);
        GEMM_SYNC();
        // phase B: stage t+2 (k0+64; wraps dead on last iter) under buf1
        QKV_STAGE(0, (k0 + 64) & (DM - 1));
        QKV_COMPUTE(1);
        GEMM_SYNC();
    }

    if (sel != 1) {
        const int act = (sel == 0);
        _Float16* Yh = (sel == 0) ? Qh : Vh;
#pragma unroll
        for (int nt = 0; nt < 4; ++nt) {
            const int col = n0 + wc * 64 + nt * 16 + fm;
            const float bvv = bias[col];
#pragma unroll
            for (int mt = 0; mt < 4; ++mt) {
                const int rbase = m0 + wr * 64 + mt * 16 + fq * 4;
#pragma unroll
                for (int r = 0; r < 4; ++r) {
                    float v = acc[mt][nt][r] + bvv;
                    if (act) v = featf(v);
                    Yh[(size_t)(rbase + r) * DM + col] = (_Float16)v;
                }
            }
        }
    } else {
        // KT-chunk layout [blk][j][t], blk = (b*16+h)*32 + chunk; act always
        const int b = m0 >> 11;
        const int cch = ((m0 & 2047) >> 6) + wr;
        const int h = (n0 >> 6) + wc;
        _Float16* hb = KTp + ((size_t)((b * 16 + h) * 32 + cch)) * 4096;
#pragma unroll
        for (int nt = 0; nt < 4; ++nt) {
            const int j = nt * 16 + fm;
            const float bvv = bias[n0 + wc * 64 + nt * 16 + fm];
#pragma unroll
            for (int mt = 0; mt < 4; ++mt) {
                float o[4];
#pragma unroll
                for (int r = 0; r < 4; ++r)
                    o[r] = featf(acc[mt][nt][r] + bvv);
                union { _Float16 h[4]; uint2 v; } pk;
#pragma unroll
                for (int r = 0; r < 4; ++r) pk.h[r] = (_Float16)o[r];
                *(uint2*)(hb + j * 64 + mt * 16 + fq * 4) = pk.v;
            }
        }
    }
}

// ---------------------------------------------------------------------------
// gemm_out: bf16 MFMA GEMM, f32 rows out. XCD-chunk swizzle (512 blocks,
// chunk 64) + conflict-free super-row layout + the same 2-phase pipeline.
// ---------------------------------------------------------------------------
__global__ __launch_bounds__(256) void gemm_out(
    const unsigned short* __restrict__ X,
    const unsigned short* __restrict__ Wt,
    const float* __restrict__ bias,
    float* __restrict__ Yf)
{
    __shared__ __align__(16) unsigned short As[2][128 * 32];
    __shared__ __align__(16) unsigned short Bs[2][128 * 32];

    const int tid = threadIdx.x;
    const int lane = tid & 63;
    const int w = tid >> 6;
    const int wr = w >> 1, wc = w & 1;
    const int fm = lane & 15;
    const int fq = lane >> 4;
    const int swz = (blockIdx.x & 7) * 64 + (blockIdx.x >> 3);
    const int n0 = (swz & 7) * 128, m0 = (swz >> 3) * 128;

    floatx4 acc[4][4];
#pragma unroll
    for (int i = 0; i < 4; ++i)
#pragma unroll
        for (int j = 0; j < 4; ++j) acc[i][j] = (floatx4){0.f, 0.f, 0.f, 0.f};

    const int sseg = tid >> 3;
    const int r0 = 2 * sseg + ((tid >> 2) & 1);
    const int g0 = (tid & 3) ^ (sseg & 3);
    const unsigned short* Xa = X + (size_t)(m0 + r0) * DM + g0 * 8;
    const unsigned short* Xb = Xa + (size_t)64 * DM;
    const unsigned short* Wa = Wt + (size_t)(n0 + r0) * DM + g0 * 8;
    const unsigned short* Wb = Wa + (size_t)64 * DM;

    QKV_STAGE(0, 0);
    GEMM_SYNC();

    for (int k0 = 0; k0 < DM; k0 += 64) {
        QKV_STAGE(1, k0 + 32);
        QKV_COMPUTE(0);
        GEMM_SYNC();
        QKV_STAGE(0, (k0 + 64) & (DM - 1));
        QKV_COMPUTE(1);
        GEMM_SYNC();
    }

#pragma unroll
    for (int nt = 0; nt < 4; ++nt) {
        const int col = n0 + wc * 64 + nt * 16 + fm;
        const float bv = bias[col];
#pragma unroll
        for (int mt = 0; mt < 4; ++mt) {
            const int rbase = m0 + wr * 64 + mt * 16 + fq * 4;
#pragma unroll
            for (int r = 0; r < 4; ++r)
                Yf[(size_t)(rbase + r) * DM + col] = acc[mt][nt][r] + bv;
        }
    }
}

// ===========================================================================
// chunk_state: Mc[j][dv] = sum_t K[t][j]*V[t][dv] (f16 plane out),
// Zc[j] = sum_t K[t][j] (f32). KTp is the f16 KT-chunk plane. LDS 18.4 KB.
// ===========================================================================
__global__ __launch_bounds__(256) void chunk_state(
    const _Float16* __restrict__ KTp, const _Float16* __restrict__ Vp,
    _Float16* __restrict__ Mc, float* __restrict__ Zc)
{
    __shared__ __align__(16) char smem[18432];
    // [0,8192) KT tile  [8192,17408) VT f16 padded  [17408,18432) scratch
    _Float16* VT = (_Float16*)(smem + 8192);
    float* scratch = (float*)(smem + 17408);

    const int blk = blockIdx.x;
    const int bh = blk / NC, c = blk % NC;
    const int b = bh / HH, h = bh % HH;
    const int tid = threadIdx.x;
    const int w = tid >> 6, lane = tid & 63;
    const int fm = lane & 15, fq = lane >> 4;
    const size_t gbase = ((size_t)(b * LL + c * CC)) * DM + h * HD;
    const _Float16* Kblk = KTp + (size_t)blk * 4096;

    stage_tile(Kblk, 64, smem, tid);

    const int lr = tid >> 2, lc0 = (tid & 3) * 16;
    // V rows (f16 plane) -> transposed VT, e-rotated scatter (2-way banks)
    {
        half8 v0 = *(const half8*)(Vp + gbase + (size_t)lr * DM + lc0);
        half8 v1 = *(const half8*)(Vp + gbase + (size_t)lr * DM + lc0 + 8);
        _Float16 va[16];
#pragma unroll
        for (int e = 0; e < 8; ++e) { va[e] = v0[e]; va[8 + e] = v1[e]; }
#pragma unroll
        for (int g = 0; g < 4; ++g)
#pragma unroll
            for (int e0 = 0; e0 < 4; ++e0) {
                const int e = g * 4 + ((e0 + tid) & 3);
                VT[(lc0 + e) * PS + lr] = va[e];
            }
    }
    // Z partials: thread (zs,zj) sums 16 t's of KT row zj (contiguous f16)
    {
        const int zj = tid & 63, zs = tid >> 6;
        half8 k0 = *(const half8*)(Kblk + zj * 64 + zs * 16);
        half8 k1 = *(const half8*)(Kblk + zj * 64 + zs * 16 + 8);
        float z = 0.f;
#pragma unroll
        for (int e = 0; e < 8; ++e) z += (float)k0[e] + (float)k1[e];
        scratch[zs * 64 + zj] = z;
    }
    __syncthreads();

    if (tid < 64) {
        Zc[(size_t)blk * 64 + tid] = scratch[tid] + scratch[64 + tid] +
                                     scratch[128 + tid] + scratch[192 + tid];
    }

    // MFMA f16: C[j][dv]; A = KT rows (swizzled tile), B = VT rows (padded)
    floatx4 acc[4];
#pragma unroll
    for (int nt = 0; nt < 4; ++nt) acc[nt] = (floatx4){0.f, 0.f, 0.f, 0.f};
    half8 aK[2];
#pragma unroll
    for (int ks = 0; ks < 2; ++ks)
        aK[ks] = frag_ldh(smem, 16 * w + fm, ks * 4 + fq);
#pragma unroll
    for (int nt = 0; nt < 4; ++nt) {
#pragma unroll
        for (int ks = 0; ks < 2; ++ks) {
            half8 bV = *(const half8*)(VT + (nt * 16 + fm) * PS + ks * 32 + fq * 8);
            acc[nt] = __builtin_amdgcn_mfma_f32_16x16x32_f16(aK[ks], bV, acc[nt], 0, 0, 0);
        }
    }
    _Float16* Mout = Mc + (size_t)blk * 4096;
#pragma unroll
    for (int nt = 0; nt < 4; ++nt) {
        const int dv = nt * 16 + fm;
#pragma unroll
        for (int r = 0; r < 4; ++r) {
            const int j = 16 * w + fq * 4 + r;
            Mout[j * 64 + dv] = (_Float16)acc[nt][r];
        }
    }
}

// ---------------------------------------------------------------------------
// exclusive prefix over chunks on the f16 Mc plane (f32 accumulator) + Z
// ---------------------------------------------------------------------------
__global__ __launch_bounds__(256) void prefix_state(
    _Float16* __restrict__ Mc, float* __restrict__ Zc)
{
    const int bh = blockIdx.x >> 4;
    const int slice = blockIdx.x & 15;
    const int off = slice * 256 + threadIdx.x;
    float run = 0.f;
    _Float16* p = Mc + (size_t)bh * NC * 4096 + off;
    for (int c = 0; c < NC; ++c) {
        const float v = (float)p[(size_t)c * 4096];
        p[(size_t)c * 4096] = (_Float16)run;
        run += v;
    }
    if (slice == 0 && threadIdx.x < 64) {
        float z = 0.f;
        float* zb = Zc + (size_t)bh * NC * 64 + threadIdx.x;
        for (int c = 0; c < NC; ++c) {
            const float v = zb[c * 64];
            zb[c * 64] = z;
            z += v;
        }
    }
}

// ===========================================================================
// chunk_attn v4 (all-f16): Q,V,KT,Mt tiles staged via global_load_lds into
// XOR-swizzled tiles; ONE barrier; A/Z/epilogue wave-local. LDS 50.3 KB
// -> 3 blk/CU. 24 MFMA/wave.
// ===========================================================================
#define ATT_Q  0
#define ATT_V  8192
#define ATT_K  16384
#define ATT_M  24576
#define ATT_A  32768   // 64 x PS f16 = 9216 B
#define ATT_Z  41984   // 64 x 65 f16 = 8320 B
__global__ __launch_bounds__(256) void chunk_attn(
    const _Float16* __restrict__ Qp, const _Float16* __restrict__ Vp,
    const _Float16* __restrict__ KTp, const _Float16* __restrict__ Mtp,
    const float* __restrict__ Zprev, unsigned short* __restrict__ Outb)
{
    __shared__ __align__(16) char smem[50304];
    _Float16* AT = (_Float16*)(smem + ATT_A);
    _Float16* Zf = (_Float16*)(smem + ATT_Z);

    const int blk = blockIdx.x;
    const int bh = blk / NC, c = blk % NC;
    const int b = bh / HH, h = bh % HH;
    const int tid = threadIdx.x;
    const int w = tid >> 6, lane = tid & 63;
    const int fm = lane & 15, fq = lane >> 4;
    const size_t gbase = ((size_t)(b * LL + c * CC)) * DM + h * HD;
    const _Float16* Kblk = KTp + (size_t)blk * 4096;

    // ---- phase 0: async staging (8 global_load_lds, zero VALU)
    stage_tile(Qp + gbase, DM, smem + ATT_Q, tid);
    stage_tile(Vp + gbase, DM, smem + ATT_V, tid);
    stage_tile(Kblk, 64, smem + ATT_K, tid);
    stage_tile(Mtp + (size_t)blk * 4096, 64, smem + ATT_M, tid);

    // Z: wave-local. Lane j of wave w computes z[i][j] for i in strip w.
    {
        const int j = lane;
        const _Float16* kr = Kblk + (size_t)j * 64;
        float run = Zprev[(size_t)blk * 64 + j];
        for (int s = 0; s < w; ++s) {   // wave-uniform bound
            half8 k0 = *(const half8*)(kr + s * 16);
            half8 k1 = *(const half8*)(kr + s * 16 + 8);
#pragma unroll
            for (int e = 0; e < 8; ++e) run += (float)k0[e] + (float)k1[e];
        }
        half8 k0 = *(const half8*)(kr + w * 16);
        half8 k1 = *(const half8*)(kr + w * 16 + 8);
        float zrow[16];
#pragma unroll
        for (int e = 0; e < 8; ++e) { run += (float)k0[e]; zrow[e] = run; }
#pragma unroll
        for (int e = 0; e < 8; ++e) { run += (float)k1[e]; zrow[8 + e] = run; }
#pragma unroll
        for (int t = 0; t < 16; ++t)
            Zf[(16 * w + t) * 65 + j] = (_Float16)zrow[t];
    }
    __syncthreads();  // the ONLY barrier (drains global_load_lds)

    // Q fragments (A-operand rows 16w+fm), reused by stage 1 and stage 2
    half8 qf[2];
#pragma unroll
    for (int ks = 0; ks < 2; ++ks)
        qf[ks] = frag_ldh(smem + ATT_Q, 16 * w + fm, ks * 4 + fq);

    // ---- stage 1: A = Q @ V^T
    floatx4 acc1[4];
#pragma unroll
    for (int nt = 0; nt < 4; ++nt) acc1[nt] = (floatx4){0.f, 0.f, 0.f, 0.f};
#pragma unroll
    for (int nt = 0; nt < 4; ++nt) {
#pragma unroll
        for (int ks = 0; ks < 2; ++ks) {
            half8 bV = frag_ldh(smem + ATT_V, nt * 16 + fm, ks * 4 + fq);
            acc1[nt] = __builtin_amdgcn_mfma_f32_16x16x32_f16(qf[ks], bV, acc1[nt], 0, 0, 0);
        }
    }

    // write tril(A) f16 (wave-local rows, padded stride, r-rotated)
#pragma unroll
    for (int nt = 0; nt < 4; ++nt) {
        const int t = nt * 16 + fm;
#pragma unroll
        for (int r0 = 0; r0 < 4; ++r0) {
            const int r = (r0 + fm) & 3;
            const int i = 16 * w + fq * 4 + r;
            AT[i * PS + t] = (_Float16)((t <= i) ? acc1[nt][r] : 0.f);
        }
    }

    // ---- stage 2: num = Q@Mt + A@KT  (no barrier: A rows are wave-local)
    floatx4 acc2[4];
#pragma unroll
    for (int nt = 0; nt < 4; ++nt) acc2[nt] = (floatx4){0.f, 0.f, 0.f, 0.f};
    {
        half8 aA[2];
#pragma unroll
        for (int ks = 0; ks < 2; ++ks)
            aA[ks] = *(const half8*)(AT + (16 * w + fm) * PS + ks * 32 + fq * 8);
#pragma unroll
        for (int nt = 0; nt < 4; ++nt) {
#pragma unroll
            for (int ks = 0; ks < 2; ++ks) {
                half8 bM = frag_ldh(smem + ATT_M, nt * 16 + fm, ks * 4 + fq);
                acc2[nt] = __builtin_amdgcn_mfma_f32_16x16x32_f16(qf[ks], bM, acc2[nt], 0, 0, 0);
            }
#pragma unroll
            for (int ks = 0; ks < 2; ++ks) {
                half8 bK = frag_ldh(smem + ATT_K, nt * 16 + fm, ks * 4 + fq);
                acc2[nt] = __builtin_amdgcn_mfma_f32_16x16x32_f16(aA[ks], bK, acc2[nt], 0, 0, 0);
            }
        }
    }

    // ---- epilogue (wave-local Zf strip + swizzled Q reads), out bf16
#pragma unroll
    for (int nt = 0; nt < 4; ++nt) {
        const int j = nt * 16 + fm;
#pragma unroll
        for (int r = 0; r < 4; ++r) {
            const int i = 16 * w + fq * 4 + r;
            const int qoff = i * 128 + (((j >> 3) ^ (i & 7)) << 4) + (j & 7) * 2;
            const float q = (float)(*(const _Float16*)(smem + ATT_Q + qoff));
            const float z = (float)Zf[i * 65 + j];
            const float denom = fmaf(q, z, EPSC);
            Outb[gbase + (size_t)i * DM + j] = f2bf(acc2[nt][r] * __builtin_amdgcn_rcpf(denom));
        }
    }
}

// ---------------------------------------------------------------------------
// Launch.  Workspace map (byte offsets, NO overlaps):
//   [  0, 16) qb   bf16 16 MB    [ 16, 32) kb 16 MB   [ 32, 48) vb 16 MB
//   [ 48, 56) Wt x4   8 MB
//   [ 56, 72) Qh   f16 16 MB     [ 72, 88) Vh  16 MB
//   [ 88,104) KTp  f16 16 MB     [104,120) Mc  16 MB
//   [120,121) Zc   f32 0.5 MB    [128,144) attnb 16 MB
// ---------------------------------------------------------------------------
extern "C" void kernel_launch(void* const* d_in, const int* in_sizes, int n_in,
                              void* d_out, int out_size, void* d_ws, size_t ws_size,
                              hipStream_t stream)
{
    (void)in_sizes; (void)n_in; (void)out_size; (void)ws_size;

    const float* queries = (const float*)d_in[0];
    const float* keys    = (const float*)d_in[1];
    const float* values  = (const float*)d_in[2];
    const float* Wq = (const float*)d_in[3];
    const float* bq = (const float*)d_in[4];
    const float* Wk = (const float*)d_in[5];
    const float* bk = (const float*)d_in[6];
    const float* Wv = (const float*)d_in[7];
    const float* bv = (const float*)d_in[8];
    const float* Wo = (const float*)d_in[9];
    const float* bo = (const float*)d_in[10];

    char* ws = (char*)d_ws;
    const size_t MB = 1u << 20;
    unsigned short* qb  = (unsigned short*)(ws);
    unsigned short* kb  = (unsigned short*)(ws + 16 * MB);
    unsigned short* vb  = (unsigned short*)(ws + 32 * MB);
    unsigned short* Wqt = (unsigned short*)(ws + 48 * MB);
    unsigned short* Wkt = (unsigned short*)(ws + 50 * MB);
    unsigned short* Wvt = (unsigned short*)(ws + 52 * MB);
    unsigned short* Wot = (unsigned short*)(ws + 54 * MB);
    _Float16* Qh  = (_Float16*)(ws + 56 * MB);
    _Float16* Vh  = (_Float16*)(ws + 72 * MB);
    _Float16* KTp = (_Float16*)(ws + 88 * MB);
    _Float16* Mc  = (_Float16*)(ws + 104 * MB);
    float* Zc     = (float*)(ws + 120 * MB);
    unsigned short* attnb = (unsigned short*)(ws + 128 * MB);

    const dim3 gblk(256);

    prep<<<dim3(2560), gblk, 0, stream>>>(queries, keys, values,
                                          Wq, Wk, Wv, Wo,
                                          qb, kb, vb, Wqt, Wkt, Wvt, Wot);

    gemm_qkv3<<<dim3(1536), gblk, 0, stream>>>(qb, kb, vb,
                                               Wqt, Wkt, Wvt, bq, bk, bv,
                                               Qh, KTp, Vh);

    chunk_state<<<dim3(BB * HH * NC), gblk, 0, stream>>>(KTp, Vh, Mc, Zc);
    prefix_state<<<dim3(BB * HH * 16), gblk, 0, stream>>>(Mc, Zc);
    chunk_attn<<<dim3(BB * HH * NC), gblk, 0, stream>>>(Qh, Vh, KTp, Mc, Zc, attnb);

    gemm_out<<<dim3(512), gblk, 0, stream>>>(attnb, Wot, bo, (float*)d_out);
}

// Round 10
// 303.010 us; speedup vs baseline: 1.2805x; 1.2805x over previous
//
#include <hip/hip_runtime.h>
#include <math.h>

// Problem constants
#define DM 1024      // d_model
#define LL 2048      // sequence length
#define BB 4         // batch
#define HH 16        // heads
#define HD 64        // head dim
#define CC 64        // chunk size
#define NC (LL / CC) // 32 chunks
#define EPSC 1e-6f
#define PS 72        // padded LDS stride (elements) for VALU-written 64-wide tiles

typedef __attribute__((ext_vector_type(8))) short short8;      // 8 bf16
typedef __attribute__((ext_vector_type(8))) _Float16 half8;    // 8 f16
typedef __attribute__((ext_vector_type(4))) float floatx4;     // MFMA acc

__device__ __forceinline__ float featf(float x) { return x > 0.f ? x + 1.f : __expf(x); }

// round-to-nearest-even f32 -> bf16 bits
__device__ __forceinline__ unsigned short f2bf(float f) {
    unsigned int u = __builtin_bit_cast(unsigned int, f);
    u = (u + 0x7FFFu + ((u >> 16) & 1u)) >> 16;
    return (unsigned short)u;
}

// 8x f32 -> 8x bf16 via hardware pk converts (RNE, matches f2bf)
__device__ __forceinline__ uint4 cvt8(float4 a, float4 b) {
    uint4 r;
    asm("v_cvt_pk_bf16_f32 %0, %1, %2" : "=v"(r.x) : "v"(a.x), "v"(a.y));
    asm("v_cvt_pk_bf16_f32 %0, %1, %2" : "=v"(r.y) : "v"(a.z), "v"(a.w));
    asm("v_cvt_pk_bf16_f32 %0, %1, %2" : "=v"(r.z) : "v"(b.x), "v"(b.y));
    asm("v_cvt_pk_bf16_f32 %0, %1, %2" : "=v"(r.w) : "v"(b.z), "v"(b.w));
    return r;
}

__device__ __forceinline__ void gload_lds16(const void* g, void* l) {
    __builtin_amdgcn_global_load_lds(
        (const __attribute__((address_space(1))) void*)g,
        (__attribute__((address_space(3))) void*)l,
        16, 0, 0);
}

// Stage a 64x64 2-byte-element tile (8 KB) global -> LDS, XOR-8 chunk swizzle
// baked into the SOURCE address. LDS: row*128B + slot*16B, slot = g ^ (row&7).
__device__ __forceinline__ void stage_tile(const void* gp_, int rowstride,
                                           char* lds_base, int tid) {
    const unsigned short* gp = (const unsigned short*)gp_;
#pragma unroll
    for (int m = 0; m < 2; ++m) {
        const int row = m * 32 + (tid >> 3);
        const int g = (tid & 7) ^ (row & 7);
        gload_lds16(gp + (size_t)row * rowstride + g * 8,
                    lds_base + m * 4096 + tid * 16);
    }
}
__device__ __forceinline__ half8 frag_ldh(const char* base, int row, int kc) {
    return *(const half8*)(base + row * 128 + (((kc) ^ (row & 7)) << 4));
}

// ===========================================================================
// prep: fused input-convert (f32->bf16, deep-MLP batched) + weight
// transpose/convert. Blocks [0,1536): convert q/k/v (512 blocks each; 8
// uint4-units per thread, all 16 float4 loads in flight before stores).
// Blocks [1536,2560): the 4 weight transposes.
// ===========================================================================
__global__ __launch_bounds__(256) void prep(
    const float* __restrict__ q, const float* __restrict__ k,
    const float* __restrict__ v,
    const float* __restrict__ W0, const float* __restrict__ W1,
    const float* __restrict__ W2, const float* __restrict__ W3,
    unsigned short* __restrict__ qb, unsigned short* __restrict__ kb,
    unsigned short* __restrict__ vb,
    unsigned short* __restrict__ T0, unsigned short* __restrict__ T1,
    unsigned short* __restrict__ T2, unsigned short* __restrict__ T3)
{
    __shared__ float tile[64][65];
    const int bid = blockIdx.x;
    const int tid = threadIdx.x;
    if (bid < 1536) {
        const int sel = bid >> 9;       // 512 blocks per tensor
        const int ib = bid & 511;
        const float* src = (sel == 0) ? q : (sel == 1) ? k : v;
        unsigned short* dst = (sel == 0) ? qb : (sel == 1) ? kb : vb;
        const size_t u0 = (size_t)ib * 2048 + tid;   // uint4-unit index
        float4 x[8], y[8];
#pragma unroll
        for (int e = 0; e < 8; ++e) {
            const size_t u = u0 + (size_t)e * 256;
            x[e] = ((const float4*)src)[u * 2];
            y[e] = ((const float4*)src)[u * 2 + 1];
        }
#pragma unroll
        for (int e = 0; e < 8; ++e)
            ((uint4*)dst)[u0 + (size_t)e * 256] = cvt8(x[e], y[e]);
    } else {
        const int tb = bid - 1536;
        const int sel = tb >> 8;        // 256 blocks per weight
        const int rem = tb & 255;
        const float* W = (sel == 0) ? W0 : (sel == 1) ? W1 : (sel == 2) ? W2 : W3;
        unsigned short* Wt = (sel == 0) ? T0 : (sel == 1) ? T1 : (sel == 2) ? T2 : T3;
        const int r0 = (rem >> 4) * 64, c0 = (rem & 15) * 64;
#pragma unroll
        for (int e = 0; e < 16; ++e) {
            const int idx = e * 256 + tid;
            const int r = idx >> 6, c = idx & 63;
            tile[r][c] = W[(size_t)(r0 + r) * DM + c0 + c];
        }
        __syncthreads();
#pragma unroll
        for (int e = 0; e < 16; ++e) {
            const int idx = e * 256 + tid;
            const int co = idx >> 6, ro = idx & 63;
            Wt[(size_t)(c0 + co) * DM + r0 + ro] = f2bf(tile[ro][co]);
        }
    }
}

// ===========================================================================
// gemm_qkv3: three projection GEMMs, one 1D dispatch. Round-7 structure
// (best measured: 82.5us, FETCH 49MB ideal, 0 bank conflicts):
//  - bijective XCD-chunk swizzle (round-5: FETCH 200->49 MB)
//  - conflict-free super-row LDS layout (round-7: 6.29M->0 conflicts)
//  - single-buffer BK=32 loop (2-phase dbuf failed 3x: occupancy loss)
// Round-9/10 change: __launch_bounds__(256, 3) -> request 3 blocks/CU
// co-residency. At 124+64=188 regs/wave only 2 blocks fit (Occ 20%); the
// per-kstep gload drain (~600-900cy) exceeds 2 blocks' MFMA cover
// (~620cy). Capping arch-VGPR at ~106 fits 3 waves/SIMD -> ~930cy cover.
// (Round-9 bench was an infra failure, not a kernel failure — resubmit.)
// sel 0: Q (act, f16)  sel 1: K (act, KT-chunk)  sel 2: V.
// ===========================================================================
__global__ __launch_bounds__(256, 3) void gemm_qkv3(
    const unsigned short* __restrict__ qb, const unsigned short* __restrict__ kb,
    const unsigned short* __restrict__ vb,
    const unsigned short* __restrict__ Wqt, const unsigned short* __restrict__ Wkt,
    const unsigned short* __restrict__ Wvt,
    const float* __restrict__ bq, const float* __restrict__ bk,
    const float* __restrict__ bv,
    _Float16* __restrict__ Qh, _Float16* __restrict__ KTp,
    _Float16* __restrict__ Vh)
{
    __shared__ __align__(16) unsigned short As[128 * 32];
    __shared__ __align__(16) unsigned short Bs[128 * 32];

    // bijective XCD swizzle: XCD x gets swz in [x*192, (x+1)*192)
    const int bid = blockIdx.x;
    const int swz = (bid & 7) * 192 + (bid >> 3);
    const int sel = swz >> 9;          // 512 tiles per sel
    const int tt = swz & 511;
    const int n0 = (tt & 7) * 128, m0 = (tt >> 3) * 128;

    const unsigned short* X = (sel == 0) ? qb : (sel == 1) ? kb : vb;
    const unsigned short* Wt = (sel == 0) ? Wqt : (sel == 1) ? Wkt : Wvt;
    const float* bias = (sel == 0) ? bq : (sel == 1) ? bk : bv;

    const int tid = threadIdx.x;
    const int lane = tid & 63;
    const int w = tid >> 6;
    const int wr = w >> 1, wc = w & 1;
    const int fm = lane & 15;
    const int fq = lane >> 4;

    floatx4 acc[4][4];
#pragma unroll
    for (int i = 0; i < 4; ++i)
#pragma unroll
        for (int j = 0; j < 4; ++j) acc[i][j] = (floatx4){0.f, 0.f, 0.f, 0.f};

    // staging map: seg t -> super-row s=t>>3, half b=(t>>2)&1, slot sl=t&3;
    // global row rr = 2s+b, col-group g = sl ^ (s&3). t+256: rr+64, same g.
    const int sseg = tid >> 3;
    const int r0 = 2 * sseg + ((tid >> 2) & 1);
    const int g0 = (tid & 3) ^ (sseg & 3);
    const unsigned short* Xa = X + (size_t)(m0 + r0) * DM + g0 * 8;
    const unsigned short* Xb = Xa + (size_t)64 * DM;
    const unsigned short* Wa = Wt + (size_t)(n0 + r0) * DM + g0 * 8;
    const unsigned short* Wb = Wa + (size_t)64 * DM;

    for (int k0 = 0; k0 < DM; k0 += 32) {
        gload_lds16(Xa + k0, As + (size_t)tid * 8);
        gload_lds16(Xb + k0, As + (size_t)(256 + tid) * 8);
        gload_lds16(Wa + k0, Bs + (size_t)tid * 8);
        gload_lds16(Wb + k0, Bs + (size_t)(256 + tid) * 8);
        __syncthreads();

        short8 af[4], bf[4];
#pragma unroll
        for (int mt = 0; mt < 4; ++mt) {
            const int rr = wr * 64 + mt * 16 + fm;
            af[mt] = *(const short8*)(As + rr * 32 + ((fq ^ ((rr >> 1) & 3)) << 3));
        }
#pragma unroll
        for (int nt = 0; nt < 4; ++nt) {
            const int rr = wc * 64 + nt * 16 + fm;
            bf[nt] = *(const short8*)(Bs + rr * 32 + ((fq ^ ((rr >> 1) & 3)) << 3));
        }
#pragma unroll
        for (int mt = 0; mt < 4; ++mt)
#pragma unroll
            for (int nt = 0; nt < 4; ++nt)
                acc[mt][nt] = __builtin_amdgcn_mfma_f32_16x16x32_bf16(
                    af[mt], bf[nt], acc[mt][nt], 0, 0, 0);
        __syncthreads();
    }

    if (sel != 1) {
        const int act = (sel == 0);
        _Float16* Yh = (sel == 0) ? Qh : Vh;
#pragma unroll
        for (int nt = 0; nt < 4; ++nt) {
            const int col = n0 + wc * 64 + nt * 16 + fm;
            const float bvv = bias[col];
#pragma unroll
            for (int mt = 0; mt < 4; ++mt) {
                const int rbase = m0 + wr * 64 + mt * 16 + fq * 4;
#pragma unroll
                for (int r = 0; r < 4; ++r) {
                    float v = acc[mt][nt][r] + bvv;
                    if (act) v = featf(v);
                    Yh[(size_t)(rbase + r) * DM + col] = (_Float16)v;
                }
            }
        }
    } else {
        // KT-chunk layout [blk][j][t], blk = (b*16+h)*32 + chunk; act always
        const int b = m0 >> 11;
        const int cch = ((m0 & 2047) >> 6) + wr;
        const int h = (n0 >> 6) + wc;
        _Float16* hb = KTp + ((size_t)((b * 16 + h) * 32 + cch)) * 4096;
#pragma unroll
        for (int nt = 0; nt < 4; ++nt) {
            const int j = nt * 16 + fm;
            const float bvv = bias[n0 + wc * 64 + nt * 16 + fm];
#pragma unroll
            for (int mt = 0; mt < 4; ++mt) {
                float o[4];
#pragma unroll
                for (int r = 0; r < 4; ++r)
                    o[r] = featf(acc[mt][nt][r] + bvv);
                union { _Float16 h[4]; uint2 v; } pk;
#pragma unroll
                for (int r = 0; r < 4; ++r) pk.h[r] = (_Float16)o[r];
                *(uint2*)(hb + j * 64 + mt * 16 + fq * 4) = pk.v;
            }
        }
    }
}

// ---------------------------------------------------------------------------
// gemm_out: bf16 MFMA GEMM, f32 rows out. Round-7 structure + the same
// 3-blocks/CU launch bound.
// ---------------------------------------------------------------------------
__global__ __launch_bounds__(256, 3) void gemm_out(
    const unsigned short* __restrict__ X,
    const unsigned short* __restrict__ Wt,
    const float* __restrict__ bias,
    float* __restrict__ Yf)
{
    __shared__ __align__(16) unsigned short As[128 * 32];
    __shared__ __align__(16) unsigned short Bs[128 * 32];

    const int tid = threadIdx.x;
    const int lane = tid & 63;
    const int w = tid >> 6;
    const int wr = w >> 1, wc = w & 1;
    const int fm = lane & 15;
    const int fq = lane >> 4;
    const int swz = (blockIdx.x & 7) * 64 + (blockIdx.x >> 3);
    const int n0 = (swz & 7) * 128, m0 = (swz >> 3) * 128;

    floatx4 acc[4][4];
#pragma unroll
    for (int i = 0; i < 4; ++i)
#pragma unroll
        for (int j = 0; j < 4; ++j) acc[i][j] = (floatx4){0.f, 0.f, 0.f, 0.f};

    const int sseg = tid >> 3;
    const int r0 = 2 * sseg + ((tid >> 2) & 1);
    const int g0 = (tid & 3) ^ (sseg & 3);
    const unsigned short* Xa = X + (size_t)(m0 + r0) * DM + g0 * 8;
    const unsigned short* Xb = Xa + (size_t)64 * DM;
    const unsigned short* Wa = Wt + (size_t)(n0 + r0) * DM + g0 * 8;
    const unsigned short* Wb = Wa + (size_t)64 * DM;

    for (int k0 = 0; k0 < DM; k0 += 32) {
        gload_lds16(Xa + k0, As + (size_t)tid * 8);
        gload_lds16(Xb + k0, As + (size_t)(256 + tid) * 8);
        gload_lds16(Wa + k0, Bs + (size_t)tid * 8);
        gload_lds16(Wb + k0, Bs + (size_t)(256 + tid) * 8);
        __syncthreads();

        short8 af[4], bf[4];
#pragma unroll
        for (int mt = 0; mt < 4; ++mt) {
            const int rr = wr * 64 + mt * 16 + fm;
            af[mt] = *(const short8*)(As + rr * 32 + ((fq ^ ((rr >> 1) & 3)) << 3));
        }
#pragma unroll
        for (int nt = 0; nt < 4; ++nt) {
            const int rr = wc * 64 + nt * 16 + fm;
            bf[nt] = *(const short8*)(Bs + rr * 32 + ((fq ^ ((rr >> 1) & 3)) << 3));
        }
#pragma unroll
        for (int mt = 0; mt < 4; ++mt)
#pragma unroll
            for (int nt = 0; nt < 4; ++nt)
                acc[mt][nt] = __builtin_amdgcn_mfma_f32_16x16x32_bf16(
                    af[mt], bf[nt], acc[mt][nt], 0, 0, 0);
        __syncthreads();
    }

#pragma unroll
    for (int nt = 0; nt < 4; ++nt) {
        const int col = n0 + wc * 64 + nt * 16 + fm;
        const float bv = bias[col];
#pragma unroll
        for (int mt = 0; mt < 4; ++mt) {
            const int rbase = m0 + wr * 64 + mt * 16 + fq * 4;
#pragma unroll
            for (int r = 0; r < 4; ++r)
                Yf[(size_t)(rbase + r) * DM + col] = acc[mt][nt][r] + bv;
        }
    }
}

// ===========================================================================
// chunk_state: Mc[j][dv] = sum_t K[t][j]*V[t][dv] (f16 plane out),
// Zc[j] = sum_t K[t][j] (f32). KTp is the f16 KT-chunk plane. LDS 18.4 KB.
// ===========================================================================
__global__ __launch_bounds__(256) void chunk_state(
    const _Float16* __restrict__ KTp, const _Float16* __restrict__ Vp,
    _Float16* __restrict__ Mc, float* __restrict__ Zc)
{
    __shared__ __align__(16) char smem[18432];
    // [0,8192) KT tile  [8192,17408) VT f16 padded  [17408,18432) scratch
    _Float16* VT = (_Float16*)(smem + 8192);
    float* scratch = (float*)(smem + 17408);

    const int blk = blockIdx.x;
    const int bh = blk / NC, c = blk % NC;
    const int b = bh / HH, h = bh % HH;
    const int tid = threadIdx.x;
    const int w = tid >> 6, lane = tid & 63;
    const int fm = lane & 15, fq = lane >> 4;
    const size_t gbase = ((size_t)(b * LL + c * CC)) * DM + h * HD;
    const _Float16* Kblk = KTp + (size_t)blk * 4096;

    stage_tile(Kblk, 64, smem, tid);

    const int lr = tid >> 2, lc0 = (tid & 3) * 16;
    // V rows (f16 plane) -> transposed VT, e-rotated scatter (2-way banks)
    {
        half8 v0 = *(const half8*)(Vp + gbase + (size_t)lr * DM + lc0);
        half8 v1 = *(const half8*)(Vp + gbase + (size_t)lr * DM + lc0 + 8);
        _Float16 va[16];
#pragma unroll
        for (int e = 0; e < 8; ++e) { va[e] = v0[e]; va[8 + e] = v1[e]; }
#pragma unroll
        for (int g = 0; g < 4; ++g)
#pragma unroll
            for (int e0 = 0; e0 < 4; ++e0) {
                const int e = g * 4 + ((e0 + tid) & 3);
                VT[(lc0 + e) * PS + lr] = va[e];
            }
    }
    // Z partials: thread (zs,zj) sums 16 t's of KT row zj (contiguous f16)
    {
        const int zj = tid & 63, zs = tid >> 6;
        half8 k0 = *(const half8*)(Kblk + zj * 64 + zs * 16);
        half8 k1 = *(const half8*)(Kblk + zj * 64 + zs * 16 + 8);
        float z = 0.f;
#pragma unroll
        for (int e = 0; e < 8; ++e) z += (float)k0[e] + (float)k1[e];
        scratch[zs * 64 + zj] = z;
    }
    __syncthreads();

    if (tid < 64) {
        Zc[(size_t)blk * 64 + tid] = scratch[tid] + scratch[64 + tid] +
                                     scratch[128 + tid] + scratch[192 + tid];
    }

    // MFMA f16: C[j][dv]; A = KT rows (swizzled tile), B = VT rows (padded)
    floatx4 acc[4];
#pragma unroll
    for (int nt = 0; nt < 4; ++nt) acc[nt] = (floatx4){0.f, 0.f, 0.f, 0.f};
    half8 aK[2];
#pragma unroll
    for (int ks = 0; ks < 2; ++ks)
        aK[ks] = frag_ldh(smem, 16 * w + fm, ks * 4 + fq);
#pragma unroll
    for (int nt = 0; nt < 4; ++nt) {
#pragma unroll
        for (int ks = 0; ks < 2; ++ks) {
            half8 bV = *(const half8*)(VT + (nt * 16 + fm) * PS + ks * 32 + fq * 8);
            acc[nt] = __builtin_amdgcn_mfma_f32_16x16x32_f16(aK[ks], bV, acc[nt], 0, 0, 0);
        }
    }
    _Float16* Mout = Mc + (size_t)blk * 4096;
#pragma unroll
    for (int nt = 0; nt < 4; ++nt) {
        const int dv = nt * 16 + fm;
#pragma unroll
        for (int r = 0; r < 4; ++r) {
            const int j = 16 * w + fq * 4 + r;
            Mout[j * 64 + dv] = (_Float16)acc[nt][r];
        }
    }
}

// ---------------------------------------------------------------------------
// exclusive prefix over chunks on the f16 Mc plane (f32 accumulator) + Z
// ---------------------------------------------------------------------------
__global__ __launch_bounds__(256) void prefix_state(
    _Float16* __restrict__ Mc, float* __restrict__ Zc)
{
    const int bh = blockIdx.x >> 4;
    const int slice = blockIdx.x & 15;
    const int off = slice * 256 + threadIdx.x;
    float run = 0.f;
    _Float16* p = Mc + (size_t)bh * NC * 4096 + off;
    for (int c = 0; c < NC; ++c) {
        const float v = (float)p[(size_t)c * 4096];
        p[(size_t)c * 4096] = (_Float16)run;
        run += v;
    }
    if (slice == 0 && threadIdx.x < 64) {
        float z = 0.f;
        float* zb = Zc + (size_t)bh * NC * 64 + threadIdx.x;
        for (int c = 0; c < NC; ++c) {
            const float v = zb[c * 64];
            zb[c * 64] = z;
            z += v;
        }
    }
}

// ===========================================================================
// chunk_attn v4 (all-f16): Q,V,KT,Mt tiles staged via global_load_lds into
// XOR-swizzled tiles; ONE barrier; A/Z/epilogue wave-local. LDS 50.3 KB
// -> 3 blk/CU. 24 MFMA/wave.
// ===========================================================================
#define ATT_Q  0
#define ATT_V  8192
#define ATT_K  16384
#define ATT_M  24576
#define ATT_A  32768   // 64 x PS f16 = 9216 B
#define ATT_Z  41984   // 64 x 65 f16 = 8320 B
__global__ __launch_bounds__(256) void chunk_attn(
    const _Float16* __restrict__ Qp, const _Float16* __restrict__ Vp,
    const _Float16* __restrict__ KTp, const _Float16* __restrict__ Mtp,
    const float* __restrict__ Zprev, unsigned short* __restrict__ Outb)
{
    __shared__ __align__(16) char smem[50304];
    _Float16* AT = (_Float16*)(smem + ATT_A);
    _Float16* Zf = (_Float16*)(smem + ATT_Z);

    const int blk = blockIdx.x;
    const int bh = blk / NC, c = blk % NC;
    const int b = bh / HH, h = bh % HH;
    const int tid = threadIdx.x;
    const int w = tid >> 6, lane = tid & 63;
    const int fm = lane & 15, fq = lane >> 4;
    const size_t gbase = ((size_t)(b * LL + c * CC)) * DM + h * HD;
    const _Float16* Kblk = KTp + (size_t)blk * 4096;

    // ---- phase 0: async staging (8 global_load_lds, zero VALU)
    stage_tile(Qp + gbase, DM, smem + ATT_Q, tid);
    stage_tile(Vp + gbase, DM, smem + ATT_V, tid);
    stage_tile(Kblk, 64, smem + ATT_K, tid);
    stage_tile(Mtp + (size_t)blk * 4096, 64, smem + ATT_M, tid);

    // Z: wave-local. Lane j of wave w computes z[i][j] for i in strip w.
    {
        const int j = lane;
        const _Float16* kr = Kblk + (size_t)j * 64;
        float run = Zprev[(size_t)blk * 64 + j];
        for (int s = 0; s < w; ++s) {   // wave-uniform bound
            half8 k0 = *(const half8*)(kr + s * 16);
            half8 k1 = *(const half8*)(kr + s * 16 + 8);
#pragma unroll
            for (int e = 0; e < 8; ++e) run += (float)k0[e] + (float)k1[e];
        }
        half8 k0 = *(const half8*)(kr + w * 16);
        half8 k1 = *(const half8*)(kr + w * 16 + 8);
        float zrow[16];
#pragma unroll
        for (int e = 0; e < 8; ++e) { run += (float)k0[e]; zrow[e] = run; }
#pragma unroll
        for (int e = 0; e < 8; ++e) { run += (float)k1[e]; zrow[8 + e] = run; }
#pragma unroll
        for (int t = 0; t < 16; ++t)
            Zf[(16 * w + t) * 65 + j] = (_Float16)zrow[t];
    }
    __syncthreads();  // the ONLY barrier (drains global_load_lds)

    // Q fragments (A-operand rows 16w+fm), reused by stage 1 and stage 2
    half8 qf[2];
#pragma unroll
    for (int ks = 0; ks < 2; ++ks)
        qf[ks] = frag_ldh(smem + ATT_Q, 16 * w + fm, ks * 4 + fq);

    // ---- stage 1: A = Q @ V^T
    floatx4 acc1[4];
#pragma unroll
    for (int nt = 0; nt < 4; ++nt) acc1[nt] = (floatx4){0.f, 0.f, 0.f, 0.f};
#pragma unroll
    for (int nt = 0; nt < 4; ++nt) {
#pragma unroll
        for (int ks = 0; ks < 2; ++ks) {
            half8 bV = frag_ldh(smem + ATT_V, nt * 16 + fm, ks * 4 + fq);
            acc1[nt] = __builtin_amdgcn_mfma_f32_16x16x32_f16(qf[ks], bV, acc1[nt], 0, 0, 0);
        }
    }

    // write tril(A) f16 (wave-local rows, padded stride, r-rotated)
#pragma unroll
    for (int nt = 0; nt < 4; ++nt) {
        const int t = nt * 16 + fm;
#pragma unroll
        for (int r0 = 0; r0 < 4; ++r0) {
            const int r = (r0 + fm) & 3;
            const int i = 16 * w + fq * 4 + r;
            AT[i * PS + t] = (_Float16)((t <= i) ? acc1[nt][r] : 0.f);
        }
    }

    // ---- stage 2: num = Q@Mt + A@KT  (no barrier: A rows are wave-local)
    floatx4 acc2[4];
#pragma unroll
    for (int nt = 0; nt < 4; ++nt) acc2[nt] = (floatx4){0.f, 0.f, 0.f, 0.f};
    {
        half8 aA[2];
#pragma unroll
        for (int ks = 0; ks < 2; ++ks)
            aA[ks] = *(const half8*)(AT + (16 * w + fm) * PS + ks * 32 + fq * 8);
#pragma unroll
        for (int nt = 0; nt < 4; ++nt) {
#pragma unroll
            for (int ks = 0; ks < 2; ++ks) {
                half8 bM = frag_ldh(smem + ATT_M, nt * 16 + fm, ks * 4 + fq);
                acc2[nt] = __builtin_amdgcn_mfma_f32_16x16x32_f16(qf[ks], bM, acc2[nt], 0, 0, 0);
            }
#pragma unroll
            for (int ks = 0; ks < 2; ++ks) {
                half8 bK = frag_ldh(smem + ATT_K, nt * 16 + fm, ks * 4 + fq);
                acc2[nt] = __builtin_amdgcn_mfma_f32_16x16x32_f16(aA[ks], bK, acc2[nt], 0, 0, 0);
            }
        }
    }

    // ---- epilogue (wave-local Zf strip + swizzled Q reads), out bf16
#pragma unroll
    for (int nt = 0; nt < 4; ++nt) {
        const int j = nt * 16 + fm;
#pragma unroll
        for (int r = 0; r < 4; ++r) {
            const int i = 16 * w + fq * 4 + r;
            const int qoff = i * 128 + (((j >> 3) ^ (i & 7)) << 4) + (j & 7) * 2;
            const float q = (float)(*(const _Float16*)(smem + ATT_Q + qoff));
            const float z = (float)Zf[i * 65 + j];
            const float denom = fmaf(q, z, EPSC);
            Outb[gbase + (size_t)i * DM + j] = f2bf(acc2[nt][r] * __builtin_amdgcn_rcpf(denom));
        }
    }
}

// ---------------------------------------------------------------------------
// Launch.  Workspace map (byte offsets, NO overlaps):
//   [  0, 16) qb   bf16 16 MB    [ 16, 32) kb 16 MB   [ 32, 48) vb 16 MB
//   [ 48, 56) Wt x4   8 MB
//   [ 56, 72) Qh   f16 16 MB     [ 72, 88) Vh  16 MB
//   [ 88,104) KTp  f16 16 MB     [104,120) Mc  16 MB
//   [120,121) Zc   f32 0.5 MB    [128,144) attnb 16 MB
// ---------------------------------------------------------------------------
extern "C" void kernel_launch(void* const* d_in, const int* in_sizes, int n_in,
                              void* d_out, int out_size, void* d_ws, size_t ws_size,
                              hipStream_t stream)
{
    (void)in_sizes; (void)n_in; (void)out_size; (void)ws_size;

    const float* queries = (const float*)d_in[0];
    const float* keys    = (const float*)d_in[1];
    const float* values  = (const float*)d_in[2];
    const float* Wq = (const float*)d_in[3];
    const float* bq = (const float*)d_in[4];
    const float* Wk = (const float*)d_in[5];
    const float* bk = (const float*)d_in[6];
    const float* Wv = (const float*)d_in[7];
    const float* bv = (const float*)d_in[8];
    const float* Wo = (const float*)d_in[9];
    const float* bo = (const float*)d_in[10];

    char* ws = (char*)d_ws;
    const size_t MB = 1u << 20;
    unsigned short* qb  = (unsigned short*)(ws);
    unsigned short* kb  = (unsigned short*)(ws + 16 * MB);
    unsigned short* vb  = (unsigned short*)(ws + 32 * MB);
    unsigned short* Wqt = (unsigned short*)(ws + 48 * MB);
    unsigned short* Wkt = (unsigned short*)(ws + 50 * MB);
    unsigned short* Wvt = (unsigned short*)(ws + 52 * MB);
    unsigned short* Wot = (unsigned short*)(ws + 54 * MB);
    _Float16* Qh  = (_Float16*)(ws + 56 * MB);
    _Float16* Vh  = (_Float16*)(ws + 72 * MB);
    _Float16* KTp = (_Float16*)(ws + 88 * MB);
    _Float16* Mc  = (_Float16*)(ws + 104 * MB);
    float* Zc     = (float*)(ws + 120 * MB);
    unsigned short* attnb = (unsigned short*)(ws + 128 * MB);

    const dim3 gblk(256);

    prep<<<dim3(2560), gblk, 0, stream>>>(queries, keys, values,
                                          Wq, Wk, Wv, Wo,
                                          qb, kb, vb, Wqt, Wkt, Wvt, Wot);

    gemm_qkv3<<<dim3(1536), gblk, 0, stream>>>(qb, kb, vb,
                                               Wqt, Wkt, Wvt, bq, bk, bv,
                                               Qh, KTp, Vh);

    chunk_state<<<dim3(BB * HH * NC), gblk, 0, stream>>>(KTp, Vh, Mc, Zc);
    prefix_state<<<dim3(BB * HH * 16), gblk, 0, stream>>>(Mc, Zc);
    chunk_attn<<<dim3(BB * HH * NC), gblk, 0, stream>>>(Qh, Vh, KTp, Mc, Zc, attnb);

    gemm_out<<<dim3(512), gblk, 0, stream>>>(attnb, Wot, bo, (float*)d_out);
}

// Round 11
// 296.392 us; speedup vs baseline: 1.3091x; 1.0223x over previous
//
#include <hip/hip_runtime.h>
#include <math.h>

// Problem constants
#define DM 1024      // d_model
#define LL 2048      // sequence length
#define BB 4         // batch
#define HH 16        // heads
#define HD 64        // head dim
#define CC 64        // chunk size
#define NC (LL / CC) // 32 chunks
#define EPSC 1e-6f
#define PS 72        // padded LDS stride (elements) for VALU-written 64-wide tiles

typedef __attribute__((ext_vector_type(8))) short short8;      // 8 bf16
typedef __attribute__((ext_vector_type(8))) _Float16 half8;    // 8 f16
typedef __attribute__((ext_vector_type(4))) float floatx4;     // MFMA acc

__device__ __forceinline__ float featf(float x) { return x > 0.f ? x + 1.f : __expf(x); }

// round-to-nearest-even f32 -> bf16 bits
__device__ __forceinline__ unsigned short f2bf(float f) {
    unsigned int u = __builtin_bit_cast(unsigned int, f);
    u = (u + 0x7FFFu + ((u >> 16) & 1u)) >> 16;
    return (unsigned short)u;
}

// 8x f32 -> 8x bf16 via hardware pk converts (RNE, matches f2bf)
__device__ __forceinline__ uint4 cvt8(float4 a, float4 b) {
    uint4 r;
    asm("v_cvt_pk_bf16_f32 %0, %1, %2" : "=v"(r.x) : "v"(a.x), "v"(a.y));
    asm("v_cvt_pk_bf16_f32 %0, %1, %2" : "=v"(r.y) : "v"(a.z), "v"(a.w));
    asm("v_cvt_pk_bf16_f32 %0, %1, %2" : "=v"(r.z) : "v"(b.x), "v"(b.y));
    asm("v_cvt_pk_bf16_f32 %0, %1, %2" : "=v"(r.w) : "v"(b.z), "v"(b.w));
    return r;
}

__device__ __forceinline__ void gload_lds16(const void* g, void* l) {
    __builtin_amdgcn_global_load_lds(
        (const __attribute__((address_space(1))) void*)g,
        (__attribute__((address_space(3))) void*)l,
        16, 0, 0);
}

// Stage a 64x64 2-byte-element tile (8 KB) global -> LDS, XOR-8 chunk swizzle
// baked into the SOURCE address. LDS: row*128B + slot*16B, slot = g ^ (row&7).
__device__ __forceinline__ void stage_tile(const void* gp_, int rowstride,
                                           char* lds_base, int tid) {
    const unsigned short* gp = (const unsigned short*)gp_;
#pragma unroll
    for (int m = 0; m < 2; ++m) {
        const int row = m * 32 + (tid >> 3);
        const int g = (tid & 7) ^ (row & 7);
        gload_lds16(gp + (size_t)row * rowstride + g * 8,
                    lds_base + m * 4096 + tid * 16);
    }
}
__device__ __forceinline__ half8 frag_ldh(const char* base, int row, int kc) {
    return *(const half8*)(base + row * 128 + (((kc) ^ (row & 7)) << 4));
}

// ===========================================================================
// prep: fused input-convert (f32->bf16, deep-MLP batched) + weight
// transpose/convert. Blocks [0,1536): convert q/k/v (512 blocks each; 8
// uint4-units per thread, all 16 float4 loads in flight before stores).
// Blocks [1536,2560): the 4 weight transposes.
// ===========================================================================
__global__ __launch_bounds__(256) void prep(
    const float* __restrict__ q, const float* __restrict__ k,
    const float* __restrict__ v,
    const float* __restrict__ W0, const float* __restrict__ W1,
    const float* __restrict__ W2, const float* __restrict__ W3,
    unsigned short* __restrict__ qb, unsigned short* __restrict__ kb,
    unsigned short* __restrict__ vb,
    unsigned short* __restrict__ T0, unsigned short* __restrict__ T1,
    unsigned short* __restrict__ T2, unsigned short* __restrict__ T3)
{
    __shared__ float tile[64][65];
    const int bid = blockIdx.x;
    const int tid = threadIdx.x;
    if (bid < 1536) {
        const int sel = bid >> 9;       // 512 blocks per tensor
        const int ib = bid & 511;
        const float* src = (sel == 0) ? q : (sel == 1) ? k : v;
        unsigned short* dst = (sel == 0) ? qb : (sel == 1) ? kb : vb;
        const size_t u0 = (size_t)ib * 2048 + tid;   // uint4-unit index
        float4 x[8], y[8];
#pragma unroll
        for (int e = 0; e < 8; ++e) {
            const size_t u = u0 + (size_t)e * 256;
            x[e] = ((const float4*)src)[u * 2];
            y[e] = ((const float4*)src)[u * 2 + 1];
        }
#pragma unroll
        for (int e = 0; e < 8; ++e)
            ((uint4*)dst)[u0 + (size_t)e * 256] = cvt8(x[e], y[e]);
    } else {
        const int tb = bid - 1536;
        const int sel = tb >> 8;        // 256 blocks per weight
        const int rem = tb & 255;
        const float* W = (sel == 0) ? W0 : (sel == 1) ? W1 : (sel == 2) ? W2 : W3;
        unsigned short* Wt = (sel == 0) ? T0 : (sel == 1) ? T1 : (sel == 2) ? T2 : T3;
        const int r0 = (rem >> 4) * 64, c0 = (rem & 15) * 64;
#pragma unroll
        for (int e = 0; e < 16; ++e) {
            const int idx = e * 256 + tid;
            const int r = idx >> 6, c = idx & 63;
            tile[r][c] = W[(size_t)(r0 + r) * DM + c0 + c];
        }
        __syncthreads();
#pragma unroll
        for (int e = 0; e < 16; ++e) {
            const int idx = e * 256 + tid;
            const int co = idx >> 6, ro = idx & 63;
            Wt[(size_t)(c0 + co) * DM + r0 + ro] = f2bf(tile[ro][co]);
        }
    }
}

// ===========================================================================
// gemm_qkv3: three projection GEMMs, one 1D dispatch. Carried techniques:
//  - bijective XCD-chunk swizzle (round-5: FETCH 200->49 MB)
//  - conflict-free super-row LDS layout (round-7: 6.29M->0 conflicts)
//  - single-buffer BK=32 loop (2-phase dbuf failed 3x: occupancy loss)
//  - 3+ blocks-worth occupancy (round-10: +12% — but VGPR squeeze to 64
//    with the 64-reg acc[4][4] forced ~6 dwords/thread scratch spill,
//    WRITE_SIZE 49->58 MB)
// Round-11: 8 waves x (64x32) sub-tiles (512 threads, acc[4][2] = 32 VGPR).
// Same 128x128 tile / LDS / staging volume / MFMA count; register total
// ~100-112 <= the 128-reg occupancy step WITHOUT spills -> true 4
// waves/SIMD. Staging: thread t owns seg t (1 A + 1 B gload).
// sel 0: Q (act, f16)  sel 1: K (act, KT-chunk)  sel 2: V.
// ===========================================================================
__global__ __launch_bounds__(512, 4) void gemm_qkv3(
    const unsigned short* __restrict__ qb, const unsigned short* __restrict__ kb,
    const unsigned short* __restrict__ vb,
    const unsigned short* __restrict__ Wqt, const unsigned short* __restrict__ Wkt,
    const unsigned short* __restrict__ Wvt,
    const float* __restrict__ bq, const float* __restrict__ bk,
    const float* __restrict__ bv,
    _Float16* __restrict__ Qh, _Float16* __restrict__ KTp,
    _Float16* __restrict__ Vh)
{
    __shared__ __align__(16) unsigned short As[128 * 32];
    __shared__ __align__(16) unsigned short Bs[128 * 32];

    // bijective XCD swizzle: XCD x gets swz in [x*192, (x+1)*192)
    const int bid = blockIdx.x;
    const int swz = (bid & 7) * 192 + (bid >> 3);
    const int sel = swz >> 9;          // 512 tiles per sel
    const int tt = swz & 511;
    const int n0 = (tt & 7) * 128, m0 = (tt >> 3) * 128;

    const unsigned short* X = (sel == 0) ? qb : (sel == 1) ? kb : vb;
    const unsigned short* Wt = (sel == 0) ? Wqt : (sel == 1) ? Wkt : Wvt;
    const float* bias = (sel == 0) ? bq : (sel == 1) ? bk : bv;

    const int tid = threadIdx.x;       // 0..511
    const int lane = tid & 63;
    const int w = tid >> 6;            // 0..7
    const int wr = w >> 2, wc = w & 3; // 2 (m) x 4 (n) wave grid
    const int fm = lane & 15;
    const int fq = lane >> 4;

    floatx4 acc[4][2];
#pragma unroll
    for (int i = 0; i < 4; ++i)
#pragma unroll
        for (int j = 0; j < 2; ++j) acc[i][j] = (floatx4){0.f, 0.f, 0.f, 0.f};

    // staging map: seg t -> super-row s=t>>3 (0..63), half b=(t>>2)&1,
    // slot sl=t&3; global row rr = 2s+b (0..127), col-group g = sl^(s&3).
    const int sseg = tid >> 3;
    const int r0 = 2 * sseg + ((tid >> 2) & 1);
    const int g0 = (tid & 3) ^ (sseg & 3);
    const unsigned short* Xa = X + (size_t)(m0 + r0) * DM + g0 * 8;
    const unsigned short* Wa = Wt + (size_t)(n0 + r0) * DM + g0 * 8;

    for (int k0 = 0; k0 < DM; k0 += 32) {
        gload_lds16(Xa + k0, As + (size_t)tid * 8);
        gload_lds16(Wa + k0, Bs + (size_t)tid * 8);
        __syncthreads();

        short8 af[4], bf[2];
#pragma unroll
        for (int mt = 0; mt < 4; ++mt) {
            const int rr = wr * 64 + mt * 16 + fm;
            af[mt] = *(const short8*)(As + rr * 32 + ((fq ^ ((rr >> 1) & 3)) << 3));
        }
#pragma unroll
        for (int nt = 0; nt < 2; ++nt) {
            const int rr = wc * 32 + nt * 16 + fm;
            bf[nt] = *(const short8*)(Bs + rr * 32 + ((fq ^ ((rr >> 1) & 3)) << 3));
        }
#pragma unroll
        for (int mt = 0; mt < 4; ++mt)
#pragma unroll
            for (int nt = 0; nt < 2; ++nt)
                acc[mt][nt] = __builtin_amdgcn_mfma_f32_16x16x32_bf16(
                    af[mt], bf[nt], acc[mt][nt], 0, 0, 0);
        __syncthreads();
    }

    if (sel != 1) {
        const int act = (sel == 0);
        _Float16* Yh = (sel == 0) ? Qh : Vh;
#pragma unroll
        for (int nt = 0; nt < 2; ++nt) {
            const int col = n0 + wc * 32 + nt * 16 + fm;
            const float bvv = bias[col];
#pragma unroll
            for (int mt = 0; mt < 4; ++mt) {
                const int rbase = m0 + wr * 64 + mt * 16 + fq * 4;
#pragma unroll
                for (int r = 0; r < 4; ++r) {
                    float v = acc[mt][nt][r] + bvv;
                    if (act) v = featf(v);
                    Yh[(size_t)(rbase + r) * DM + col] = (_Float16)v;
                }
            }
        }
    } else {
        // KT-chunk layout [blk][j][t], blk = (b*16+h)*32 + chunk; act always.
        // Wave covers cols [n0+wc*32, n0+wc*32+32): head h = (n0>>6)+(wc>>1),
        // j = (wc&1)*32 + nt*16 + fm. Chunk cch = ((m0&2047)>>6) + wr.
        const int b = m0 >> 11;
        const int cch = ((m0 & 2047) >> 6) + wr;
        const int h = (n0 >> 6) + (wc >> 1);
        _Float16* hb = KTp + ((size_t)((b * 16 + h) * 32 + cch)) * 4096;
#pragma unroll
        for (int nt = 0; nt < 2; ++nt) {
            const int j = (wc & 1) * 32 + nt * 16 + fm;
            const float bvv = bias[n0 + wc * 32 + nt * 16 + fm];
#pragma unroll
            for (int mt = 0; mt < 4; ++mt) {
                float o[4];
#pragma unroll
                for (int r = 0; r < 4; ++r)
                    o[r] = featf(acc[mt][nt][r] + bvv);
                union { _Float16 h[4]; uint2 v; } pk;
#pragma unroll
                for (int r = 0; r < 4; ++r) pk.h[r] = (_Float16)o[r];
                *(uint2*)(hb + j * 64 + mt * 16 + fq * 4) = pk.v;
            }
        }
    }
}

// ---------------------------------------------------------------------------
// gemm_out: bf16 MFMA GEMM, f32 rows out. Same 8-wave 64x32 decomposition,
// XCD-chunk swizzle (512 blocks, chunk 64), super-row LDS layout.
// ---------------------------------------------------------------------------
__global__ __launch_bounds__(512, 4) void gemm_out(
    const unsigned short* __restrict__ X,
    const unsigned short* __restrict__ Wt,
    const float* __restrict__ bias,
    float* __restrict__ Yf)
{
    __shared__ __align__(16) unsigned short As[128 * 32];
    __shared__ __align__(16) unsigned short Bs[128 * 32];

    const int tid = threadIdx.x;
    const int lane = tid & 63;
    const int w = tid >> 6;
    const int wr = w >> 2, wc = w & 3;
    const int fm = lane & 15;
    const int fq = lane >> 4;
    const int swz = (blockIdx.x & 7) * 64 + (blockIdx.x >> 3);
    const int n0 = (swz & 7) * 128, m0 = (swz >> 3) * 128;

    floatx4 acc[4][2];
#pragma unroll
    for (int i = 0; i < 4; ++i)
#pragma unroll
        for (int j = 0; j < 2; ++j) acc[i][j] = (floatx4){0.f, 0.f, 0.f, 0.f};

    const int sseg = tid >> 3;
    const int r0 = 2 * sseg + ((tid >> 2) & 1);
    const int g0 = (tid & 3) ^ (sseg & 3);
    const unsigned short* Xa = X + (size_t)(m0 + r0) * DM + g0 * 8;
    const unsigned short* Wa = Wt + (size_t)(n0 + r0) * DM + g0 * 8;

    for (int k0 = 0; k0 < DM; k0 += 32) {
        gload_lds16(Xa + k0, As + (size_t)tid * 8);
        gload_lds16(Wa + k0, Bs + (size_t)tid * 8);
        __syncthreads();

        short8 af[4], bf[2];
#pragma unroll
        for (int mt = 0; mt < 4; ++mt) {
            const int rr = wr * 64 + mt * 16 + fm;
            af[mt] = *(const short8*)(As + rr * 32 + ((fq ^ ((rr >> 1) & 3)) << 3));
        }
#pragma unroll
        for (int nt = 0; nt < 2; ++nt) {
            const int rr = wc * 32 + nt * 16 + fm;
            bf[nt] = *(const short8*)(Bs + rr * 32 + ((fq ^ ((rr >> 1) & 3)) << 3));
        }
#pragma unroll
        for (int mt = 0; mt < 4; ++mt)
#pragma unroll
            for (int nt = 0; nt < 2; ++nt)
                acc[mt][nt] = __builtin_amdgcn_mfma_f32_16x16x32_bf16(
                    af[mt], bf[nt], acc[mt][nt], 0, 0, 0);
        __syncthreads();
    }

#pragma unroll
    for (int nt = 0; nt < 2; ++nt) {
        const int col = n0 + wc * 32 + nt * 16 + fm;
        const float bv = bias[col];
#pragma unroll
        for (int mt = 0; mt < 4; ++mt) {
            const int rbase = m0 + wr * 64 + mt * 16 + fq * 4;
#pragma unroll
            for (int r = 0; r < 4; ++r)
                Yf[(size_t)(rbase + r) * DM + col] = acc[mt][nt][r] + bv;
        }
    }
}

// ===========================================================================
// chunk_state: Mc[j][dv] = sum_t K[t][j]*V[t][dv] (f16 plane out),
// Zc[j] = sum_t K[t][j] (f32). KTp is the f16 KT-chunk plane. LDS 18.4 KB.
// ===========================================================================
__global__ __launch_bounds__(256) void chunk_state(
    const _Float16* __restrict__ KTp, const _Float16* __restrict__ Vp,
    _Float16* __restrict__ Mc, float* __restrict__ Zc)
{
    __shared__ __align__(16) char smem[18432];
    // [0,8192) KT tile  [8192,17408) VT f16 padded  [17408,18432) scratch
    _Float16* VT = (_Float16*)(smem + 8192);
    float* scratch = (float*)(smem + 17408);

    const int blk = blockIdx.x;
    const int bh = blk / NC, c = blk % NC;
    const int b = bh / HH, h = bh % HH;
    const int tid = threadIdx.x;
    const int w = tid >> 6, lane = tid & 63;
    const int fm = lane & 15, fq = lane >> 4;
    const size_t gbase = ((size_t)(b * LL + c * CC)) * DM + h * HD;
    const _Float16* Kblk = KTp + (size_t)blk * 4096;

    stage_tile(Kblk, 64, smem, tid);

    const int lr = tid >> 2, lc0 = (tid & 3) * 16;
    // V rows (f16 plane) -> transposed VT, e-rotated scatter (2-way banks)
    {
        half8 v0 = *(const half8*)(Vp + gbase + (size_t)lr * DM + lc0);
        half8 v1 = *(const half8*)(Vp + gbase + (size_t)lr * DM + lc0 + 8);
        _Float16 va[16];
#pragma unroll
        for (int e = 0; e < 8; ++e) { va[e] = v0[e]; va[8 + e] = v1[e]; }
#pragma unroll
        for (int g = 0; g < 4; ++g)
#pragma unroll
            for (int e0 = 0; e0 < 4; ++e0) {
                const int e = g * 4 + ((e0 + tid) & 3);
                VT[(lc0 + e) * PS + lr] = va[e];
            }
    }
    // Z partials: thread (zs,zj) sums 16 t's of KT row zj (contiguous f16)
    {
        const int zj = tid & 63, zs = tid >> 6;
        half8 k0 = *(const half8*)(Kblk + zj * 64 + zs * 16);
        half8 k1 = *(const half8*)(Kblk + zj * 64 + zs * 16 + 8);
        float z = 0.f;
#pragma unroll
        for (int e = 0; e < 8; ++e) z += (float)k0[e] + (float)k1[e];
        scratch[zs * 64 + zj] = z;
    }
    __syncthreads();

    if (tid < 64) {
        Zc[(size_t)blk * 64 + tid] = scratch[tid] + scratch[64 + tid] +
                                     scratch[128 + tid] + scratch[192 + tid];
    }

    // MFMA f16: C[j][dv]; A = KT rows (swizzled tile), B = VT rows (padded)
    floatx4 acc[4];
#pragma unroll
    for (int nt = 0; nt < 4; ++nt) acc[nt] = (floatx4){0.f, 0.f, 0.f, 0.f};
    half8 aK[2];
#pragma unroll
    for (int ks = 0; ks < 2; ++ks)
        aK[ks] = frag_ldh(smem, 16 * w + fm, ks * 4 + fq);
#pragma unroll
    for (int nt = 0; nt < 4; ++nt) {
#pragma unroll
        for (int ks = 0; ks < 2; ++ks) {
            half8 bV = *(const half8*)(VT + (nt * 16 + fm) * PS + ks * 32 + fq * 8);
            acc[nt] = __builtin_amdgcn_mfma_f32_16x16x32_f16(aK[ks], bV, acc[nt], 0, 0, 0);
        }
    }
    _Float16* Mout = Mc + (size_t)blk * 4096;
#pragma unroll
    for (int nt = 0; nt < 4; ++nt) {
        const int dv = nt * 16 + fm;
#pragma unroll
        for (int r = 0; r < 4; ++r) {
            const int j = 16 * w + fq * 4 + r;
            Mout[j * 64 + dv] = (_Float16)acc[nt][r];
        }
    }
}

// ---------------------------------------------------------------------------
// exclusive prefix over chunks on the f16 Mc plane (f32 accumulator) + Z
// ---------------------------------------------------------------------------
__global__ __launch_bounds__(256) void prefix_state(
    _Float16* __restrict__ Mc, float* __restrict__ Zc)
{
    const int bh = blockIdx.x >> 4;
    const int slice = blockIdx.x & 15;
    const int off = slice * 256 + threadIdx.x;
    float run = 0.f;
    _Float16* p = Mc + (size_t)bh * NC * 4096 + off;
    for (int c = 0; c < NC; ++c) {
        const float v = (float)p[(size_t)c * 4096];
        p[(size_t)c * 4096] = (_Float16)run;
        run += v;
    }
    if (slice == 0 && threadIdx.x < 64) {
        float z = 0.f;
        float* zb = Zc + (size_t)bh * NC * 64 + threadIdx.x;
        for (int c = 0; c < NC; ++c) {
            const float v = zb[c * 64];
            zb[c * 64] = z;
            z += v;
        }
    }
}

// ===========================================================================
// chunk_attn v4 (all-f16): Q,V,KT,Mt tiles staged via global_load_lds into
// XOR-swizzled tiles; ONE barrier; A/Z/epilogue wave-local. LDS 50.3 KB
// -> 3 blk/CU. 24 MFMA/wave.
// ===========================================================================
#define ATT_Q  0
#define ATT_V  8192
#define ATT_K  16384
#define ATT_M  24576
#define ATT_A  32768   // 64 x PS f16 = 9216 B
#define ATT_Z  41984   // 64 x 65 f16 = 8320 B
__global__ __launch_bounds__(256) void chunk_attn(
    const _Float16* __restrict__ Qp, const _Float16* __restrict__ Vp,
    const _Float16* __restrict__ KTp, const _Float16* __restrict__ Mtp,
    const float* __restrict__ Zprev, unsigned short* __restrict__ Outb)
{
    __shared__ __align__(16) char smem[50304];
    _Float16* AT = (_Float16*)(smem + ATT_A);
    _Float16* Zf = (_Float16*)(smem + ATT_Z);

    const int blk = blockIdx.x;
    const int bh = blk / NC, c = blk % NC;
    const int b = bh / HH, h = bh % HH;
    const int tid = threadIdx.x;
    const int w = tid >> 6, lane = tid & 63;
    const int fm = lane & 15, fq = lane >> 4;
    const size_t gbase = ((size_t)(b * LL + c * CC)) * DM + h * HD;
    const _Float16* Kblk = KTp + (size_t)blk * 4096;

    // ---- phase 0: async staging (8 global_load_lds, zero VALU)
    stage_tile(Qp + gbase, DM, smem + ATT_Q, tid);
    stage_tile(Vp + gbase, DM, smem + ATT_V, tid);
    stage_tile(Kblk, 64, smem + ATT_K, tid);
    stage_tile(Mtp + (size_t)blk * 4096, 64, smem + ATT_M, tid);

    // Z: wave-local. Lane j of wave w computes z[i][j] for i in strip w.
    {
        const int j = lane;
        const _Float16* kr = Kblk + (size_t)j * 64;
        float run = Zprev[(size_t)blk * 64 + j];
        for (int s = 0; s < w; ++s) {   // wave-uniform bound
            half8 k0 = *(const half8*)(kr + s * 16);
            half8 k1 = *(const half8*)(kr + s * 16 + 8);
#pragma unroll
            for (int e = 0; e < 8; ++e) run += (float)k0[e] + (float)k1[e];
        }
        half8 k0 = *(const half8*)(kr + w * 16);
        half8 k1 = *(const half8*)(kr + w * 16 + 8);
        float zrow[16];
#pragma unroll
        for (int e = 0; e < 8; ++e) { run += (float)k0[e]; zrow[e] = run; }
#pragma unroll
        for (int e = 0; e < 8; ++e) { run += (float)k1[e]; zrow[8 + e] = run; }
#pragma unroll
        for (int t = 0; t < 16; ++t)
            Zf[(16 * w + t) * 65 + j] = (_Float16)zrow[t];
    }
    __syncthreads();  // the ONLY barrier (drains global_load_lds)

    // Q fragments (A-operand rows 16w+fm), reused by stage 1 and stage 2
    half8 qf[2];
#pragma unroll
    for (int ks = 0; ks < 2; ++ks)
        qf[ks] = frag_ldh(smem + ATT_Q, 16 * w + fm, ks * 4 + fq);

    // ---- stage 1: A = Q @ V^T
    floatx4 acc1[4];
#pragma unroll
    for (int nt = 0; nt < 4; ++nt) acc1[nt] = (floatx4){0.f, 0.f, 0.f, 0.f};
#pragma unroll
    for (int nt = 0; nt < 4; ++nt) {
#pragma unroll
        for (int ks = 0; ks < 2; ++ks) {
            half8 bV = frag_ldh(smem + ATT_V, nt * 16 + fm, ks * 4 + fq);
            acc1[nt] = __builtin_amdgcn_mfma_f32_16x16x32_f16(qf[ks], bV, acc1[nt], 0, 0, 0);
        }
    }

    // write tril(A) f16 (wave-local rows, padded stride, r-rotated)
#pragma unroll
    for (int nt = 0; nt < 4; ++nt) {
        const int t = nt * 16 + fm;
#pragma unroll
        for (int r0 = 0; r0 < 4; ++r0) {
            const int r = (r0 + fm) & 3;
            const int i = 16 * w + fq * 4 + r;
            AT[i * PS + t] = (_Float16)((t <= i) ? acc1[nt][r] : 0.f);
        }
    }

    // ---- stage 2: num = Q@Mt + A@KT  (no barrier: A rows are wave-local)
    floatx4 acc2[4];
#pragma unroll
    for (int nt = 0; nt < 4; ++nt) acc2[nt] = (floatx4){0.f, 0.f, 0.f, 0.f};
    {
        half8 aA[2];
#pragma unroll
        for (int ks = 0; ks < 2; ++ks)
            aA[ks] = *(const half8*)(AT + (16 * w + fm) * PS + ks * 32 + fq * 8);
#pragma unroll
        for (int nt = 0; nt < 4; ++nt) {
#pragma unroll
            for (int ks = 0; ks < 2; ++ks) {
                half8 bM = frag_ldh(smem + ATT_M, nt * 16 + fm, ks * 4 + fq);
                acc2[nt] = __builtin_amdgcn_mfma_f32_16x16x32_f16(qf[ks], bM, acc2[nt], 0, 0, 0);
            }
#pragma unroll
            for (int ks = 0; ks < 2; ++ks) {
                half8 bK = frag_ldh(smem + ATT_K, nt * 16 + fm, ks * 4 + fq);
                acc2[nt] = __builtin_amdgcn_mfma_f32_16x16x32_f16(aA[ks], bK, acc2[nt], 0, 0, 0);
            }
        }
    }

    // ---- epilogue (wave-local Zf strip + swizzled Q reads), out bf16
#pragma unroll
    for (int nt = 0; nt < 4; ++nt) {
        const int j = nt * 16 + fm;
#pragma unroll
        for (int r = 0; r < 4; ++r) {
            const int i = 16 * w + fq * 4 + r;
            const int qoff = i * 128 + (((j >> 3) ^ (i & 7)) << 4) + (j & 7) * 2;
            const float q = (float)(*(const _Float16*)(smem + ATT_Q + qoff));
            const float z = (float)Zf[i * 65 + j];
            const float denom = fmaf(q, z, EPSC);
            Outb[gbase + (size_t)i * DM + j] = f2bf(acc2[nt][r] * __builtin_amdgcn_rcpf(denom));
        }
    }
}

// ---------------------------------------------------------------------------
// Launch.  Workspace map (byte offsets, NO overlaps):
//   [  0, 16) qb   bf16 16 MB    [ 16, 32) kb 16 MB   [ 32, 48) vb 16 MB
//   [ 48, 56) Wt x4   8 MB
//   [ 56, 72) Qh   f16 16 MB     [ 72, 88) Vh  16 MB
//   [ 88,104) KTp  f16 16 MB     [104,120) Mc  16 MB
//   [120,121) Zc   f32 0.5 MB    [128,144) attnb 16 MB
// ---------------------------------------------------------------------------
extern "C" void kernel_launch(void* const* d_in, const int* in_sizes, int n_in,
                              void* d_out, int out_size, void* d_ws, size_t ws_size,
                              hipStream_t stream)
{
    (void)in_sizes; (void)n_in; (void)out_size; (void)ws_size;

    const float* queries = (const float*)d_in[0];
    const float* keys    = (const float*)d_in[1];
    const float* values  = (const float*)d_in[2];
    const float* Wq = (const float*)d_in[3];
    const float* bq = (const float*)d_in[4];
    const float* Wk = (const float*)d_in[5];
    const float* bk = (const float*)d_in[6];
    const float* Wv = (const float*)d_in[7];
    const float* bv = (const float*)d_in[8];
    const float* Wo = (const float*)d_in[9];
    const float* bo = (const float*)d_in[10];

    char* ws = (char*)d_ws;
    const size_t MB = 1u << 20;
    unsigned short* qb  = (unsigned short*)(ws);
    unsigned short* kb  = (unsigned short*)(ws + 16 * MB);
    unsigned short* vb  = (unsigned short*)(ws + 32 * MB);
    unsigned short* Wqt = (unsigned short*)(ws + 48 * MB);
    unsigned short* Wkt = (unsigned short*)(ws + 50 * MB);
    unsigned short* Wvt = (unsigned short*)(ws + 52 * MB);
    unsigned short* Wot = (unsigned short*)(ws + 54 * MB);
    _Float16* Qh  = (_Float16*)(ws + 56 * MB);
    _Float16* Vh  = (_Float16*)(ws + 72 * MB);
    _Float16* KTp = (_Float16*)(ws + 88 * MB);
    _Float16* Mc  = (_Float16*)(ws + 104 * MB);
    float* Zc     = (float*)(ws + 120 * MB);
    unsigned short* attnb = (unsigned short*)(ws + 128 * MB);

    const dim3 gblk(256);
    const dim3 gblk2(512);

    prep<<<dim3(2560), gblk, 0, stream>>>(queries, keys, values,
                                          Wq, Wk, Wv, Wo,
                                          qb, kb, vb, Wqt, Wkt, Wvt, Wot);

    gemm_qkv3<<<dim3(1536), gblk2, 0, stream>>>(qb, kb, vb,
                                                Wqt, Wkt, Wvt, bq, bk, bv,
                                                Qh, KTp, Vh);

    chunk_state<<<dim3(BB * HH * NC), gblk, 0, stream>>>(KTp, Vh, Mc, Zc);
    prefix_state<<<dim3(BB * HH * 16), gblk, 0, stream>>>(Mc, Zc);
    chunk_attn<<<dim3(BB * HH * NC), gblk, 0, stream>>>(Qh, Vh, KTp, Mc, Zc, attnb);

    gemm_out<<<dim3(512), gblk2, 0, stream>>>(attnb, Wot, bo, (float*)d_out);
}